// Round 10
// baseline (105.079 us; speedup 1.0000x reference)
//
#include <hip/hip_runtime.h>
#include <hip/hip_bf16.h>

// Self-guided-filter loss, fused per 32x32 tile. v10 = v9 stage-1 + v8 stage-2:
//  - P2: global -> h1 horizontal 11-sums (v9 verbatim, float4 global loads)
//  - P4: vertical 11-sums h1 -> A,B; 154 tasks, 3-row chains, sub-rows in regs
//  - P6': vertical 11-sums A,B -> V2; 88 tasks, 4-row chains, sub-rows in regs
//  - P7': horizontal 11-sums over V2 + finalize; 256 tasks, 8 LDS reads each
//  - x-tile prefetched per image (issue-early); flit in 4 named regs
//  - XCD-chunked bijective block swizzle (halo sharing in per-XCD L2)
// LDS 34.8KB -> 4 blocks/CU. (8,3,512,512) fp32, RADIUS=5 (k=11), EPS=1e-6.

#define W 512
#define TB 32
#define H1STR 48   // h1: 52 rows, cols 0..41 valid (42..47 junk, never read)
#define ABSTR 44   // A,B: 42 rows, cols 0..41 valid (42,43 junk; only cols<=41 consumed)
#define V2STR 44   // V2: 32 rows, cols 0..41 valid (42,43 junk, never consumed)

#define O_H1X 0        // 52*48 = 2496
#define O_H1Y 2496
#define O_A   4992     // 42*44 = 1848
#define O_B   6840
#define O_V2A 0        // aliases h1x (dead after P4); 32*44 = 1408
#define O_V2B 2496     // aliases h1y
#define S_FLOATS 8688  // 34,752 B -> 4 blocks/CU

#define NBLK_X 16
#define NBLK_Y 16
#define NPLANES 24
#define NWG (NBLK_X*NBLK_Y*NPLANES)     // 6144, % 8 == 0
#define NPARTIALS NWG
#define TOTAL_ELEMS 6291456.0
#define INV121 (1.0f/121.0f)

__device__ __forceinline__ float4 ld4(const float* p) { return *(const float4*)p; }

__global__ __launch_bounds__(256, 4) void sgf_loss_kernel(
    const float* __restrict__ gen, const float* __restrict__ ir,
    const float* __restrict__ vi, float* __restrict__ partials)
{
    __shared__ __align__(16) float S[S_FLOATS];
    const int tid = threadIdx.x;

    // XCD-chunked bijective swizzle (NWG % 8 == 0)
    const int bid = blockIdx.x;
    const int swz = (bid & 7) * (NWG / 8) + (bid >> 3);
    const int tx0 = (swz & (NBLK_X - 1)) * TB;
    const int ty0 = ((swz / NBLK_X) & (NBLK_Y - 1)) * TB;
    const size_t pbase = (size_t)(swz / (NBLK_X * NBLK_Y)) * (W * W);

    // per-thread output pixel (used by prefetch + P7')
    const int prow = tid >> 3;            // 0..31
    const int pc4  = (tid & 7) * 4;       // 0,4,..,28

    float acc = 0.0f;
    float F0 = 0.f, F1 = 0.f, F2 = 0.f, F3 = 0.f;   // flit state (named regs)

    #pragma unroll 1
    for (int img = 0; img < 3; ++img) {
        const float* __restrict__ X =
            (img == 0 ? ir : (img == 1 ? vi : gen)) + pbase;

        // T14 issue-early: this thread's output-pixel quad (used only in P7')
        float4 xv = ld4(X + (size_t)(ty0 + prow) * W + (tx0 + pc4));

        __syncthreads();   // V2 (aliased h1) reads in prev P7' done before P2 writes

        // ---- P2: global -> h1 horizontal 11-sums of x and x^2 (v9 verbatim).
        // 312 tasks: 52 rows x 6 col-groups of 8.
        for (int t = tid; t < 312; t += 256) {
            int r = t / 6, cg = t - r * 6;
            int j0 = cg * 8;
            float* hx = &S[O_H1X + r * H1STR + j0];
            float* hy = &S[O_H1Y + r * H1STR + j0];
            int gy = ty0 - 10 + r;
            if ((unsigned)gy >= (unsigned)W) {
                float4 z = make_float4(0.f, 0.f, 0.f, 0.f);
                *(float4*)hx = z; *(float4*)(hx + 4) = z;
                *(float4*)hy = z; *(float4*)(hy + 4) = z;
                continue;
            }
            const float* Xr = X + (size_t)gy * W;
            int gx0 = tx0 - 12 + j0;           // 16B-aligned
            float w[20];
            if (gx0 >= 0 && gx0 + 20 <= W) {
                const float4* p = (const float4*)(Xr + gx0);
                float4 v0 = p[0], v1 = p[1], v2 = p[2], v3 = p[3], v4 = p[4];
                w[0]=v0.x;  w[1]=v0.y;  w[2]=v0.z;  w[3]=v0.w;
                w[4]=v1.x;  w[5]=v1.y;  w[6]=v1.z;  w[7]=v1.w;
                w[8]=v2.x;  w[9]=v2.y;  w[10]=v2.z; w[11]=v2.w;
                w[12]=v3.x; w[13]=v3.y; w[14]=v3.z; w[15]=v3.w;
                w[16]=v4.x; w[17]=v4.y; w[18]=v4.z; w[19]=v4.w;
            } else {
                #pragma unroll
                for (int k = 0; k < 20; ++k) {
                    int gx = gx0 + k;
                    w[k] = ((unsigned)gx < (unsigned)W) ? Xr[gx] : 0.f;
                }
            }
            float o[8], u[8];
            float s = w[2]+w[3]+w[4]+w[5]+w[6]+w[7]+w[8]+w[9]+w[10]+w[11]+w[12];
            o[0] = s;
            #pragma unroll
            for (int k = 1; k < 8; ++k) { s += w[12+k] - w[1+k]; o[k] = s; }
            float sq[20];
            #pragma unroll
            for (int k = 2; k < 20; ++k) sq[k] = w[k] * w[k];
            float s2 = sq[2]+sq[3]+sq[4]+sq[5]+sq[6]+sq[7]+sq[8]+sq[9]+sq[10]+sq[11]+sq[12];
            u[0] = s2;
            #pragma unroll
            for (int k = 1; k < 8; ++k) { s2 += sq[12+k] - sq[1+k]; u[k] = s2; }
            *(float4*)hx       = make_float4(o[0], o[1], o[2], o[3]);
            *(float4*)(hx + 4) = make_float4(o[4], o[5], o[6], o[7]);
            *(float4*)hy       = make_float4(u[0], u[1], u[2], u[3]);
            *(float4*)(hy + 4) = make_float4(u[4], u[5], u[6], u[7]);
        }
        __syncthreads();

        // ---- P4: vertical 11-sums over h1 -> A,B. 154 tasks, 3-row chains;
        // subtract-rows (d=0..2) held in named regs (no LDS re-read).
        if (tid < 154) {
            int chunk = tid / 11, cg = tid - chunk * 11;
            int q0 = chunk * 3, c4 = cg * 4;
            float mv0 = ((unsigned)(tx0-5+c4+0) < (unsigned)W) ? INV121 : 0.f;
            float mv1 = ((unsigned)(tx0-5+c4+1) < (unsigned)W) ? INV121 : 0.f;
            float mv2 = ((unsigned)(tx0-5+c4+2) < (unsigned)W) ? INV121 : 0.f;
            float mv3 = ((unsigned)(tx0-5+c4+3) < (unsigned)W) ? INV121 : 0.f;
            const float* hx = &S[O_H1X + c4];
            const float* hy = &S[O_H1Y + c4];
            float4 sX0 = ld4(hx + (q0+0)*H1STR), sY0 = ld4(hy + (q0+0)*H1STR);
            float4 sX1 = ld4(hx + (q0+1)*H1STR), sY1 = ld4(hy + (q0+1)*H1STR);
            float4 sX2 = ld4(hx + (q0+2)*H1STR), sY2 = ld4(hy + (q0+2)*H1STR);
            float sx0 = sX0.x + sX1.x + sX2.x, sy0 = sY0.x + sY1.x + sY2.x;
            float sx1 = sX0.y + sX1.y + sX2.y, sy1 = sY0.y + sY1.y + sY2.y;
            float sx2 = sX0.z + sX1.z + sX2.z, sy2 = sY0.z + sY1.z + sY2.z;
            float sx3 = sX0.w + sX1.w + sX2.w, sy3 = sY0.w + sY1.w + sY2.w;
            #pragma unroll
            for (int d = 3; d < 10; ++d) {
                float4 xn = ld4(hx + (q0+d)*H1STR);
                float4 yn = ld4(hy + (q0+d)*H1STR);
                sx0+=xn.x; sx1+=xn.y; sx2+=xn.z; sx3+=xn.w;
                sy0+=yn.x; sy1+=yn.y; sy2+=yn.z; sy3+=yn.w;
            }
#define P4_ROW(J, SUBX, SUBY, DOSUB)                                          \
            {                                                                 \
                int q = q0 + (J);                                             \
                float4 xn = ld4(hx + (q+10)*H1STR);                           \
                float4 yn = ld4(hy + (q+10)*H1STR);                           \
                sx0+=xn.x; sx1+=xn.y; sx2+=xn.z; sx3+=xn.w;                   \
                sy0+=yn.x; sy1+=yn.y; sy2+=yn.z; sy3+=yn.w;                   \
                int gy = ty0 - 5 + q;                                         \
                float4 av, bv;                                                \
                if ((unsigned)gy < (unsigned)W) {                             \
                    float m0=sx0*mv0, c0=sy0*mv0, m1=sx1*mv1, c1=sy1*mv1;     \
                    float m2=sx2*mv2, c2=sy2*mv2, m3=sx3*mv3, c3=sy3*mv3;     \
                    float va0=fmaf(-m0,m0,c0), va1=fmaf(-m1,m1,c1);           \
                    float va2=fmaf(-m2,m2,c2), va3=fmaf(-m3,m3,c3);           \
                    float a0=va0*__builtin_amdgcn_rcpf(va0+1e-6f);            \
                    float a1=va1*__builtin_amdgcn_rcpf(va1+1e-6f);            \
                    float a2=va2*__builtin_amdgcn_rcpf(va2+1e-6f);            \
                    float a3=va3*__builtin_amdgcn_rcpf(va3+1e-6f);            \
                    av = make_float4(a0,a1,a2,a3);                            \
                    bv = make_float4(fmaf(-a0,m0,m0), fmaf(-a1,m1,m1),        \
                                     fmaf(-a2,m2,m2), fmaf(-a3,m3,m3));       \
                } else { av = make_float4(0.f,0.f,0.f,0.f); bv = av; }        \
                *(float4*)&S[O_A + q*ABSTR + c4] = av;                        \
                *(float4*)&S[O_B + q*ABSTR + c4] = bv;                        \
                if (DOSUB) {                                                  \
                    sx0-=SUBX.x; sx1-=SUBX.y; sx2-=SUBX.z; sx3-=SUBX.w;       \
                    sy0-=SUBY.x; sy1-=SUBY.y; sy2-=SUBY.z; sy3-=SUBY.w;       \
                }                                                             \
            }
            P4_ROW(0, sX0, sY0, 1)
            P4_ROW(1, sX1, sY1, 1)
            P4_ROW(2, sX2, sY2, 0)
#undef P4_ROW
        }
        __syncthreads();

        // ---- P6': vertical 11-sums over A,B -> V2 (aliases h1, dead).
        // 88 tasks: ch 0..7 (V2 rows 4ch..4ch+3), cg 0..10 (cols 4cg..4cg+3);
        // subtract-rows (d=0..3) held in named regs.
        if (tid < 88) {
            int ch = tid / 11, cg = tid - ch * 11;
            int c4 = cg * 4, p0 = ch * 4;
            const float* Ap = &S[O_A + c4];
            const float* Bp = &S[O_B + c4];
            float4 pA0 = ld4(Ap + (p0+0)*ABSTR), pB0 = ld4(Bp + (p0+0)*ABSTR);
            float4 pA1 = ld4(Ap + (p0+1)*ABSTR), pB1 = ld4(Bp + (p0+1)*ABSTR);
            float4 pA2 = ld4(Ap + (p0+2)*ABSTR), pB2 = ld4(Bp + (p0+2)*ABSTR);
            float4 pA3 = ld4(Ap + (p0+3)*ABSTR), pB3 = ld4(Bp + (p0+3)*ABSTR);
            float sa0 = pA0.x+pA1.x+pA2.x+pA3.x, sb0 = pB0.x+pB1.x+pB2.x+pB3.x;
            float sa1 = pA0.y+pA1.y+pA2.y+pA3.y, sb1 = pB0.y+pB1.y+pB2.y+pB3.y;
            float sa2 = pA0.z+pA1.z+pA2.z+pA3.z, sb2 = pB0.z+pB1.z+pB2.z+pB3.z;
            float sa3 = pA0.w+pA1.w+pA2.w+pA3.w, sb3 = pB0.w+pB1.w+pB2.w+pB3.w;
            #pragma unroll
            for (int d = 4; d < 10; ++d) {
                float4 a = ld4(Ap + (p0+d)*ABSTR);
                float4 b = ld4(Bp + (p0+d)*ABSTR);
                sa0+=a.x; sa1+=a.y; sa2+=a.z; sa3+=a.w;
                sb0+=b.x; sb1+=b.y; sb2+=b.z; sb3+=b.w;
            }
#define P6_ROW(J, SUBA, SUBB, DOSUB)                                          \
            {                                                                 \
                int p = p0 + (J);                                             \
                float4 a = ld4(Ap + (p+10)*ABSTR);                            \
                float4 b = ld4(Bp + (p+10)*ABSTR);                            \
                sa0+=a.x; sa1+=a.y; sa2+=a.z; sa3+=a.w;                       \
                sb0+=b.x; sb1+=b.y; sb2+=b.z; sb3+=b.w;                       \
                *(float4*)&S[O_V2A + p*V2STR + c4] = make_float4(sa0,sa1,sa2,sa3); \
                *(float4*)&S[O_V2B + p*V2STR + c4] = make_float4(sb0,sb1,sb2,sb3); \
                if (DOSUB) {                                                  \
                    sa0-=SUBA.x; sa1-=SUBA.y; sa2-=SUBA.z; sa3-=SUBA.w;       \
                    sb0-=SUBB.x; sb1-=SUBB.y; sb2-=SUBB.z; sb3-=SUBB.w;       \
                }                                                             \
            }
            P6_ROW(0, pA0, pB0, 1)
            P6_ROW(1, pA1, pB1, 1)
            P6_ROW(2, pA2, pB2, 1)
            P6_ROW(3, pA3, pB3, 0)
#undef P6_ROW
        }
        __syncthreads();

        // ---- P7': horizontal 11-sums over V2 + finalize. 256 tasks (all waves):
        // out row prow, out cols pc4..pc4+3; window V2 cols j..j+10 (V2 col0 = img tx0-5).
        {
            const float* va = &S[O_V2A + prow * V2STR + pc4];
            const float* vb = &S[O_V2B + prow * V2STR + pc4];
            float4 a0 = ld4(va), a1 = ld4(va+4), a2 = ld4(va+8), a3 = ld4(va+12);
            float4 b0 = ld4(vb), b1 = ld4(vb+4), b2 = ld4(vb+8), b3 = ld4(vb+12);
            float oa0 = a0.x+a0.y+a0.z+a0.w + a1.x+a1.y+a1.z+a1.w + a2.x+a2.y+a2.z;
            float oa1 = oa0 + a2.w - a0.x;
            float oa2 = oa1 + a3.x - a0.y;
            float oa3 = oa2 + a3.y - a0.z;
            float ob0 = b0.x+b0.y+b0.z+b0.w + b1.x+b1.y+b1.z+b1.w + b2.x+b2.y+b2.z;
            float ob1 = ob0 + b2.w - b0.x;
            float ob2 = ob1 + b3.x - b0.y;
            float ob3 = ob2 + b3.y - b0.z;
            float t0 = fmaf(oa0, xv.x, ob0), g0 = fmaf(-t0, INV121, xv.x);
            float t1 = fmaf(oa1, xv.y, ob1), g1 = fmaf(-t1, INV121, xv.y);
            float t2 = fmaf(oa2, xv.z, ob2), g2 = fmaf(-t2, INV121, xv.z);
            float t3 = fmaf(oa3, xv.w, ob3), g3 = fmaf(-t3, INV121, xv.w);
            if (img == 0) {
                F0 = fabsf(g0); F1 = fabsf(g1); F2 = fabsf(g2); F3 = fabsf(g3);
            } else if (img == 1) {
                F0 = fmaxf(F0, fabsf(g0)); F1 = fmaxf(F1, fabsf(g1));
                F2 = fmaxf(F2, fabsf(g2)); F3 = fmaxf(F3, fabsf(g3));
            } else {
                acc += fabsf(g0 - F0) + fabsf(g1 - F1)
                     + fabsf(g2 - F2) + fabsf(g3 - F3);
            }
        }
    } // img loop

    // block reduction: wave shuffle + cross-wave via LDS
    #pragma unroll
    for (int off = 32; off > 0; off >>= 1) acc += __shfl_down(acc, off);
    __syncthreads();                // all P7' LDS reads done before S reuse
    if ((tid & 63) == 0) S[tid >> 6] = acc;
    __syncthreads();
    if (tid == 0)
        partials[swz] = S[0] + S[1] + S[2] + S[3];
}

__global__ __launch_bounds__(256) void sgf_final_reduce(
    const float* __restrict__ partials, float* __restrict__ out)
{
    __shared__ double sd[256];
    int tid = threadIdx.x;
    double s = 0.0;
    for (int i = tid; i < NPARTIALS; i += 256) s += (double)partials[i];
    sd[tid] = s;
    __syncthreads();
    for (int off = 128; off > 0; off >>= 1) {
        if (tid < off) sd[tid] += sd[tid + off];
        __syncthreads();
    }
    if (tid == 0) out[0] = (float)(sd[0] * (1.0 / TOTAL_ELEMS));
}

extern "C" void kernel_launch(void* const* d_in, const int* in_sizes, int n_in,
                              void* d_out, int out_size, void* d_ws, size_t ws_size,
                              hipStream_t stream) {
    const float* gen = (const float*)d_in[0];
    const float* ir  = (const float*)d_in[1];
    const float* vi  = (const float*)d_in[2];
    float* partials = (float*)d_ws;   // 6144 floats = 24 KB

    sgf_loss_kernel<<<dim3(NWG), dim3(256), 0, stream>>>(gen, ir, vi, partials);
    sgf_final_reduce<<<1, dim3(256), 0, stream>>>(partials, (float*)d_out);
}